// Round 11
// baseline (270.705 us; speedup 1.0000x reference)
//
#include <hip/hip_runtime.h>
#include <hip/hip_bf16.h>
#include <math.h>
#include <stddef.h>

#define DEV __device__ __forceinline__
__device__ const float BNS = 0.99999500003749968f; // 1/sqrt(1+1e-5)

typedef __bf16 bf16x8 __attribute__((ext_vector_type(8)));
typedef float  f32x4  __attribute__((ext_vector_type(4)));

DEV unsigned short f2bs(float v){
  union{ __hip_bfloat16 b; unsigned short u; } c; c.b=__float2bfloat16(v); return c.u;
}
DEV float bs2f(unsigned short u){
  union{ unsigned short u; __hip_bfloat16 b; } c; c.u=u; return __bfloat162float(c.b);
}

// Geometry: B=2, M=256 -> 512 bm groups, N=64 pts, KNN=16, CIN=64,
// edge1 O=64, edge2 O=128, SUMM=192, CALIB=64, EXP=256/512, OUT=256. f32 I/O.
// Split-bf16 activation layout: [row][2][K] ushort (hi row, lo row), row=bm*64+n.

// ------- fused prep: 6 weight splits + 3 head transposes in one launch ------
__global__ __launch_bounds__(256) void k_prep(const float* __restrict__ e1_w,
    const float* __restrict__ e2_w, const float* __restrict__ cal1_w,
    const float* __restrict__ cal2_w, const float* __restrict__ exp1_w,
    const float* __restrict__ exp2_w, unsigned short* __restrict__ Whi,
    unsigned short* __restrict__ Wlo,
    const float* __restrict__ red_w, const float* __restrict__ sc1_w,
    const float* __restrict__ sc2_w, float* __restrict__ Wt_red,
    float* __restrict__ Wt_s1, float* __restrict__ Wt_s2){
  __shared__ float s[32][33];
  int bid = blockIdx.x;
  if(bid < 896){
    const float* src; unsigned short *hi,*lo; int mode, O=0, i0;
    if(bid<32)      { src=e1_w;  hi=Whi;       lo=Wlo;       mode=1; O= 64; i0=bid*256; }
    else if(bid<96) { src=e2_w;  hi=Whi+8192;  lo=Wlo+8192;  mode=1; O=128; i0=(bid-32)*256; }
    else if(bid<144){ src=cal1_w;hi=Whi+24576; lo=Wlo+24576; mode=0;        i0=(bid-96)*256; }
    else if(bid<192){ src=cal2_w;hi=Whi+36864; lo=Wlo+36864; mode=0;        i0=(bid-144)*256; }
    else if(bid<384){ src=exp1_w;hi=Whi+49152; lo=Wlo+49152; mode=0;        i0=(bid-192)*256; }
    else            { src=exp2_w;hi=Whi+98304; lo=Wlo+98304; mode=0;        i0=(bid-384)*256; }
    int i = i0 + threadIdx.x;
    float v;
    if(mode==0) v = src[i];
    else { // edge rows: [W1 ; W2-W1] over [2O][64]
      int row=i>>6, c=i&63;
      v = (row<O) ? src[row*128+c] : (src[(row-O)*128+64+c]-src[(row-O)*128+c]);
    }
    unsigned short h=f2bs(v); hi[i]=h; lo[i]=f2bs(v-bs2f(h));
  } else {
    int lb = bid-896;
    const float* in; float* out; int O,K;
    if(lb<128){ in=red_w; out=Wt_red; O=256; K=512; }
    else if(lb<192){ in=sc1_w; out=Wt_s1; O=256; K=256; lb-=128; }
    else { in=sc2_w; out=Wt_s2; O=256; K=256; lb-=192; }
    int nt=O>>5;
    int to=lb%nt, tk=lb/nt;
    int c=threadIdx.x&31, r8=threadIdx.x>>5;
    #pragma unroll
    for(int p=0;p<4;p++){
      int r=r8+p*8;
      s[r][c]=in[(size_t)(to*32+r)*K + tk*32 + c];
    }
    __syncthreads();
    #pragma unroll
    for(int p=0;p<4;p++){
      int r=r8+p*8;
      out[(size_t)(tk*32+r)*O + to*32 + c]=s[c][r];
    }
  }
}

// -------- fused knn + edge1 + edge2: per bm, all in LDS ---------------------
__global__ __launch_bounds__(256) void k_knne12(const float* __restrict__ xyz,
    const float* __restrict__ feats,
    const unsigned short* __restrict__ W1h, const unsigned short* __restrict__ W1l,
    const unsigned short* __restrict__ W2h, const unsigned short* __restrict__ W2l,
    int* __restrict__ idxo, const float* __restrict__ g1, const float* __restrict__ b1,
    const float* __restrict__ g2, const float* __restrict__ b2,
    unsigned short* __restrict__ cat){
  __shared__ float bufA[64*65];   // zs
  __shared__ float bufB[64*65];   // ds
  __shared__ __align__(16) unsigned short sb[64*136]; // x split -> e1out split
  __shared__ int   ips[64*16];
  __shared__ float sx0[64], sx1[64], sx2[64], sxx[64];
  int bm = blockIdx.x;
  int tid = threadIdx.x, n = tid&63, s = tid>>6;
  int wid = tid>>6, lane = tid&63;
  int l15 = lane&15, q = lane>>4;
  if(s==0){
    const float* xp = xyz + (size_t)(bm*64+n)*3;
    float px=xp[0], py=xp[1], pz=xp[2];
    sx0[n]=px; sx1[n]=py; sx2[n]=pz; sxx[n]=px*px+py*py+pz*pz;
  }
  __syncthreads();
  // ---- phase 1: wave-local top-16 (pd in registers, 4 lanes/point) ----
  {
    int p = lane>>2, seg = lane&3;
    int n1 = wid*16 + p;
    float px=sx0[n1], py=sx1[n1], pz=sx2[n1], xxn=sxx[n1];
    float pdr[16];
    #pragma unroll
    for(int t=0;t<16;t++){
      int m = seg*16+t;
      pdr[t] = 2.f*(px*sx0[m]+py*sx1[m]+pz*sx2[m]) - xxn - sxx[m];
    }
    for(int j=0;j<16;j++){
      float bv=-3.4e38f; int bi=seg*16;
      #pragma unroll
      for(int t=0;t<16;t++){ if(pdr[t]>bv){bv=pdr[t]; bi=seg*16+t;} }  // strict >: lowest idx
      float ov=__shfl_xor(bv,1); int oi=__shfl_xor(bi,1);
      if(ov>bv || (ov==bv && oi<bi)){bv=ov;bi=oi;}
      ov=__shfl_xor(bv,2); oi=__shfl_xor(bi,2);
      if(ov>bv || (ov==bv && oi<bi)){bv=ov;bi=oi;}
      if(seg==0) ips[n1*16+j]=bi;
      if((bi>>4)==seg) pdr[bi&15]=-3.4e38f;
    }
  }
  // ---- phase 2: split x into sb ----
  {
    unsigned short* r = sb + n*136;
    if(s==0){
      float px=sx0[n], py=sx1[n], pz=sx2[n];
      unsigned short h;
      h=f2bs(px); r[0]=h; r[64]=f2bs(px-bs2f(h));
      h=f2bs(py); r[1]=h; r[65]=f2bs(py-bs2f(h));
      h=f2bs(pz); r[2]=h; r[66]=f2bs(pz-bs2f(h));
    }
    const float* fp = feats + (size_t)(bm*64+n)*61;
    #pragma unroll
    for(int t=0;t<16;t++){
      int cc = s*16+t;
      if(cc<61){
        float v=fp[cc]; unsigned short h=f2bs(v);
        r[3+cc]=h; r[64+3+cc]=f2bs(v-bs2f(h));
      }
    }
  }
  __syncthreads();
  #pragma unroll
  for(int t=0;t<4;t++) idxo[bm*1024 + tid*4 + t] = ips[tid*4 + t];
  // ---- phase 3: edge1 MFMA ----
  {
    int rbase = ((wid<2)?0:64) + (wid&1)*32;
    f32x4 acc[2][4];
    #pragma unroll
    for(int a=0;a<2;a++)
      #pragma unroll
      for(int d=0;d<4;d++) acc[a][d]=(f32x4){0.f,0.f,0.f,0.f};
    #pragma unroll
    for(int kc=0;kc<2;kc++){
      int k0=kc*32;
      size_t a0=(size_t)(rbase+l15)*64 + k0 + q*8;
      size_t a1=(size_t)(rbase+16+l15)*64 + k0 + q*8;
      bf16x8 a0h=*(const bf16x8*)(W1h+a0), a0l=*(const bf16x8*)(W1l+a0);
      bf16x8 a1h=*(const bf16x8*)(W1h+a1), a1l=*(const bf16x8*)(W1l+a1);
      #pragma unroll
      for(int nt=0;nt<4;nt++){
        int row = nt*16 + l15;
        bf16x8 bh = *(const bf16x8*)&sb[row*136 + k0 + q*8];
        bf16x8 bl = *(const bf16x8*)&sb[row*136 + 64 + k0 + q*8];
        acc[0][nt]=__builtin_amdgcn_mfma_f32_16x16x32_bf16(a0h,bh,acc[0][nt],0,0,0);
        acc[0][nt]=__builtin_amdgcn_mfma_f32_16x16x32_bf16(a0h,bl,acc[0][nt],0,0,0);
        acc[0][nt]=__builtin_amdgcn_mfma_f32_16x16x32_bf16(a0l,bh,acc[0][nt],0,0,0);
        acc[1][nt]=__builtin_amdgcn_mfma_f32_16x16x32_bf16(a1h,bh,acc[1][nt],0,0,0);
        acc[1][nt]=__builtin_amdgcn_mfma_f32_16x16x32_bf16(a1h,bl,acc[1][nt],0,0,0);
        acc[1][nt]=__builtin_amdgcn_mfma_f32_16x16x32_bf16(a1l,bh,acc[1][nt],0,0,0);
      }
    }
    __syncthreads();
    float* dst = (wid<2)? bufA : bufB;
    int ro = (wid&1)*32;
    #pragma unroll
    for(int mt=0;mt<2;mt++)
      #pragma unroll
      for(int nt=0;nt<4;nt++)
        #pragma unroll
        for(int rr=0;rr<4;rr++)
          dst[(ro+mt*16+q*4+rr)*65 + nt*16+l15] = acc[mt][nt][rr];
  }
  __syncthreads();
  // ---- phase 4: gather edge1; write cats[0:64) + e1out split into sb ----
  {
    int o = lane;
    float sc = g1[o]*BNS, bi = b1[o];
    #pragma unroll 4
    for(int j=0;j<16;j++){
      int nn = wid*16 + j;
      const int* ip = &ips[nn*16];
      float mz = -3.4e38f;
      #pragma unroll
      for(int k=0;k<16;k++) mz = fmaxf(mz, bufA[o*65 + ip[k]]);
      float v = fmaxf(sc*(mz + bufB[o*65 + nn]) + bi, 0.f);
      unsigned short hv = f2bs(v), lv = f2bs(v - bs2f(hv));
      size_t cb = ((size_t)bm*64+nn)*384 + o;
      cat[cb] = hv; cat[cb+192] = lv;
      sb[nn*136 + o] = hv; sb[nn*136 + 64 + o] = lv;  // x dead after phase 3
    }
  }
  // ---- phase 5: edge2 (2 chunks of 64 o) from sb ----
  for(int ch=0; ch<2; ch++){
    __syncthreads();
    int rbase = ((wid<2)?0:128) + ch*64 + (wid&1)*32;
    f32x4 acc[2][4];
    #pragma unroll
    for(int a=0;a<2;a++)
      #pragma unroll
      for(int d=0;d<4;d++) acc[a][d]=(f32x4){0.f,0.f,0.f,0.f};
    #pragma unroll
    for(int kc=0;kc<2;kc++){
      int k0=kc*32;
      size_t a0=(size_t)(rbase+l15)*64 + k0 + q*8;
      size_t a1=(size_t)(rbase+16+l15)*64 + k0 + q*8;
      bf16x8 a0h=*(const bf16x8*)(W2h+a0), a0l=*(const bf16x8*)(W2l+a0);
      bf16x8 a1h=*(const bf16x8*)(W2h+a1), a1l=*(const bf16x8*)(W2l+a1);
      #pragma unroll
      for(int nt=0;nt<4;nt++){
        int row = nt*16 + l15;
        bf16x8 bh = *(const bf16x8*)&sb[row*136 + k0 + q*8];
        bf16x8 bl = *(const bf16x8*)&sb[row*136 + 64 + k0 + q*8];
        acc[0][nt]=__builtin_amdgcn_mfma_f32_16x16x32_bf16(a0h,bh,acc[0][nt],0,0,0);
        acc[0][nt]=__builtin_amdgcn_mfma_f32_16x16x32_bf16(a0h,bl,acc[0][nt],0,0,0);
        acc[0][nt]=__builtin_amdgcn_mfma_f32_16x16x32_bf16(a0l,bh,acc[0][nt],0,0,0);
        acc[1][nt]=__builtin_amdgcn_mfma_f32_16x16x32_bf16(a1h,bh,acc[1][nt],0,0,0);
        acc[1][nt]=__builtin_amdgcn_mfma_f32_16x16x32_bf16(a1h,bl,acc[1][nt],0,0,0);
        acc[1][nt]=__builtin_amdgcn_mfma_f32_16x16x32_bf16(a1l,bh,acc[1][nt],0,0,0);
      }
    }
    __syncthreads();
    float* dst = (wid<2)? bufA : bufB;
    int ro = (wid&1)*32;
    #pragma unroll
    for(int mt=0;mt<2;mt++)
      #pragma unroll
      for(int nt=0;nt<4;nt++)
        #pragma unroll
        for(int rr=0;rr<4;rr++)
          dst[(ro+mt*16+q*4+rr)*65 + nt*16+l15] = acc[mt][nt][rr];
    __syncthreads();
    int o = ch*64 + lane;
    float sc = g2[o]*BNS, bi = b2[o];
    #pragma unroll 4
    for(int j=0;j<16;j++){
      int nn = wid*16 + j;
      const int* ip = &ips[nn*16];
      float mz = -3.4e38f;
      #pragma unroll
      for(int k=0;k<16;k++) mz = fmaxf(mz, bufA[lane*65 + ip[k]]);
      float v = fmaxf(sc*(mz + bufB[lane*65 + nn]) + bi, 0.f);
      unsigned short hv = f2bs(v);
      size_t cb = ((size_t)bm*64+nn)*384 + 64 + o;
      cat[cb] = hv; cat[cb+192] = f2bs(v - bs2f(hv));
    }
  }
}

// ---------------- fused cal1+cal2+gate: one block = 128 rows ----------------
__global__ __launch_bounds__(256) void k_cal(
    const unsigned short* __restrict__ Whi, const unsigned short* __restrict__ Wlo,
    unsigned short* __restrict__ cats,
    const float* __restrict__ c1g, const float* __restrict__ c1b,
    const float* __restrict__ c2bias){
  const unsigned short* c1w_h = Whi+24576; const unsigned short* c1w_l = Wlo+24576;
  const unsigned short* c2w_h = Whi+36864; const unsigned short* c2w_l = Wlo+36864;
  __shared__ __align__(16) unsigned short sW[64*64];
  __shared__ __align__(16) unsigned short sX[128*64];
  __shared__ __align__(16) unsigned short c1L[128*136];
  int rt = blockIdx.x;
  int tid = threadIdx.x, wid = tid>>6, lane = tid&63;
  int l15 = lane&15, q = lane>>4;
  f32x4 acc1[8];
  #pragma unroll
  for(int d=0;d<8;d++) acc1[d]=(f32x4){0.f,0.f,0.f,0.f};
  size_t xbase = (size_t)rt*128*384;
  for(int kc=0;kc<6;kc++){
    int k0=kc*32;
    __syncthreads();
    #pragma unroll
    for(int i=0;i<2;i++){
      int U = tid + i*256;
      int r = U>>3, up = U&7, u = up ^ (r&7);
      const unsigned short* src = (u<4)
        ? (c1w_h + (size_t)r*192 + k0 + u*8)
        : (c1w_l + (size_t)r*192 + k0 + (u-4)*8);
      *(uint4*)&sW[U*8] = *(const uint4*)src;
    }
    #pragma unroll
    for(int i=0;i<4;i++){
      int U = tid + i*256;
      int r = U>>3, up = U&7, u = up ^ (r&7);
      const unsigned short* src = cats + xbase + (size_t)r*384
        + (u<4 ? (size_t)(k0 + u*8) : (size_t)(192 + k0 + (u-4)*8));
      *(uint4*)&sX[U*8] = *(const uint4*)src;
    }
    __syncthreads();
    int o = wid*16 + l15;
    bf16x8 wh = *(const bf16x8*)&sW[(o*8 + ((  q) ^ (o&7)))*8];
    bf16x8 wl = *(const bf16x8*)&sW[(o*8 + ((4+q) ^ (o&7)))*8];
    #pragma unroll
    for(int nf=0;nf<8;nf++){
      int r = nf*16 + l15;
      bf16x8 xh = *(const bf16x8*)&sX[(r*8 + ((  q) ^ (r&7)))*8];
      bf16x8 xl = *(const bf16x8*)&sX[(r*8 + ((4+q) ^ (r&7)))*8];
      acc1[nf]=__builtin_amdgcn_mfma_f32_16x16x32_bf16(wh,xh,acc1[nf],0,0,0);
      acc1[nf]=__builtin_amdgcn_mfma_f32_16x16x32_bf16(wh,xl,acc1[nf],0,0,0);
      acc1[nf]=__builtin_amdgcn_mfma_f32_16x16x32_bf16(wl,xh,acc1[nf],0,0,0);
    }
  }
  {
    int ob0 = wid*16 + q*4;
    float s0[4], b0[4];
    #pragma unroll
    for(int r=0;r<4;r++){ s0[r]=c1g[ob0+r]*BNS; b0[r]=c1b[ob0+r]; }
    #pragma unroll
    for(int nf=0;nf<8;nf++){
      int n = nf*16 + l15;
      unsigned short hv[4], lv[4];
      #pragma unroll
      for(int r=0;r<4;r++){
        float v = fmaxf(acc1[nf][r]*s0[r]+b0[r], 0.f);
        hv[r]=f2bs(v); lv[r]=f2bs(v - bs2f(hv[r]));
      }
      *(ushort4*)&c1L[n*136 + ob0]      = make_ushort4(hv[0],hv[1],hv[2],hv[3]);
      *(ushort4*)&c1L[n*136 + 64 + ob0] = make_ushort4(lv[0],lv[1],lv[2],lv[3]);
    }
  }
  __syncthreads();
  f32x4 acc2[3][8];
  #pragma unroll
  for(int a=0;a<3;a++)
    #pragma unroll
    for(int d=0;d<8;d++) acc2[a][d]=(f32x4){0.f,0.f,0.f,0.f};
  #pragma unroll
  for(int kc=0;kc<2;kc++){
    int k0=kc*32;
    bf16x8 ah[3], al[3];
    #pragma unroll
    for(int mt=0;mt<3;mt++){
      int o = wid*48 + mt*16 + l15;
      ah[mt]=*(const bf16x8*)(c2w_h + (size_t)o*64 + k0 + q*8);
      al[mt]=*(const bf16x8*)(c2w_l + (size_t)o*64 + k0 + q*8);
    }
    #pragma unroll
    for(int nf=0;nf<8;nf++){
      int n = nf*16 + l15;
      bf16x8 bh = *(const bf16x8*)&c1L[n*136 + k0 + q*8];
      bf16x8 bl = *(const bf16x8*)&c1L[n*136 + 64 + k0 + q*8];
      #pragma unroll
      for(int mt=0;mt<3;mt++){
        acc2[mt][nf]=__builtin_amdgcn_mfma_f32_16x16x32_bf16(ah[mt],bh,acc2[mt][nf],0,0,0);
        acc2[mt][nf]=__builtin_amdgcn_mfma_f32_16x16x32_bf16(ah[mt],bl,acc2[mt][nf],0,0,0);
        acc2[mt][nf]=__builtin_amdgcn_mfma_f32_16x16x32_bf16(al[mt],bh,acc2[mt][nf],0,0,0);
      }
    }
  }
  #pragma unroll
  for(int mt=0;mt<3;mt++){
    int ob0 = wid*48 + mt*16 + q*4;
    float bi[4];
    #pragma unroll
    for(int r=0;r<4;r++) bi[r]=c2bias[ob0+r];
    #pragma unroll
    for(int nf=0;nf<8;nf++){
      size_t row = (size_t)rt*128 + nf*16 + l15;
      size_t rb = row*384;
      ushort4 hv = *(ushort4*)(cats + rb + ob0);
      ushort4 lv = *(ushort4*)(cats + rb + 192 + ob0);
      unsigned short h[4]={hv.x,hv.y,hv.z,hv.w}, l[4]={lv.x,lv.y,lv.z,lv.w};
      #pragma unroll
      for(int r=0;r<4;r++){
        float g = 1.f/(1.f+__expf(-(acc2[mt][nf][r]+bi[r])));
        float f = (bs2f(h[r])+bs2f(l[r]))*g;
        h[r]=f2bs(f); l[r]=f2bs(f-bs2f(h[r]));
      }
      *(ushort4*)(cats + rb + ob0)       = make_ushort4(h[0],h[1],h[2],h[3]);
      *(ushort4*)(cats + rb + 192 + ob0) = make_ushort4(l[0],l[1],l[2],l[3]);
    }
  }
}

// ---------------- LDS-tiled split-bf16 MFMA GEMM ---------------------------
template<int K, int BO, int EPI>
__global__ __launch_bounds__(256) void k_mm2(
    const unsigned short* __restrict__ Whi, const unsigned short* __restrict__ Wlo,
    const unsigned short* __restrict__ X, void* __restrict__ Og,
    const float* __restrict__ sg, const float* __restrict__ bg, int O){
  constexpr int WO = BO/4;
  constexpr int MT = WO/16;
  constexpr int WUNITS = BO*8;
  __shared__ __align__(16) unsigned short sW[BO*64];
  __shared__ __align__(16) unsigned short sX[128*64];
  int rt = blockIdx.x;
  int o0 = blockIdx.y*BO;
  int tid = threadIdx.x, wid = tid>>6, lane = tid&63;
  int l15 = lane&15, q = lane>>4;
  f32x4 acc[MT][8];
  #pragma unroll
  for(int a=0;a<MT;a++)
    #pragma unroll
    for(int d=0;d<8;d++) acc[a][d]=(f32x4){0.f,0.f,0.f,0.f};
  size_t xbase = (size_t)rt*128*2*K;
  for(int kc=0; kc<K/32; kc++){
    int k0 = kc*32;
    __syncthreads();
    #pragma unroll
    for(int i=0;i<WUNITS/256;i++){
      int U = tid + i*256;
      int r = U>>3, up = U&7, u = up ^ (r&7);
      const unsigned short* src = (u<4)
        ? (Whi + (size_t)(o0+r)*K + k0 + u*8)
        : (Wlo + (size_t)(o0+r)*K + k0 + (u-4)*8);
      *(uint4*)&sW[U*8] = *(const uint4*)src;
    }
    #pragma unroll
    for(int i=0;i<4;i++){
      int U = tid + i*256;
      int r = U>>3, up = U&7, u = up ^ (r&7);
      const unsigned short* src = X + xbase + (size_t)r*2*K
        + (u<4 ? (size_t)(k0 + u*8) : (size_t)(K + k0 + (u-4)*8));
      *(uint4*)&sX[U*8] = *(const uint4*)src;
    }
    __syncthreads();
    bf16x8 wf[MT][2];
    #pragma unroll
    for(int mt=0;mt<MT;mt++){
      int o = wid*WO + mt*16 + l15;
      wf[mt][0] = *(const bf16x8*)&sW[(o*8 + ((  q) ^ (o&7)))*8];
      wf[mt][1] = *(const bf16x8*)&sW[(o*8 + ((4+q) ^ (o&7)))*8];
    }
    #pragma unroll
    for(int nf=0;nf<8;nf++){
      int r = nf*16 + l15;
      bf16x8 xh = *(const bf16x8*)&sX[(r*8 + ((  q) ^ (r&7)))*8];
      bf16x8 xl = *(const bf16x8*)&sX[(r*8 + ((4+q) ^ (r&7)))*8];
      #pragma unroll
      for(int mt=0;mt<MT;mt++){
        acc[mt][nf]=__builtin_amdgcn_mfma_f32_16x16x32_bf16(wf[mt][0],xh,acc[mt][nf],0,0,0);
        acc[mt][nf]=__builtin_amdgcn_mfma_f32_16x16x32_bf16(wf[mt][0],xl,acc[mt][nf],0,0,0);
        acc[mt][nf]=__builtin_amdgcn_mfma_f32_16x16x32_bf16(wf[mt][1],xh,acc[mt][nf],0,0,0);
      }
    }
  }
  if(EPI==0){
    unsigned short* ob = (unsigned short*)Og;
    #pragma unroll
    for(int mt=0;mt<MT;mt++){
      int ob0 = o0 + wid*WO + mt*16 + q*4;
      float s0[4], b0[4];
      #pragma unroll
      for(int r=0;r<4;r++){ s0[r]=sg[ob0+r]*BNS; b0[r]=bg[ob0+r]; }
      #pragma unroll
      for(int nf=0;nf<8;nf++){
        size_t row = (size_t)rt*128 + nf*16 + l15;
        size_t rb = row*2*O;
        unsigned short hv[4], lv[4];
        #pragma unroll
        for(int r=0;r<4;r++){
          float v = fmaxf(acc[mt][nf][r]*s0[r]+b0[r], 0.f);
          hv[r]=f2bs(v); lv[r]=f2bs(v - bs2f(hv[r]));
        }
        *(ushort4*)(ob + rb + ob0)     = make_ushort4(hv[0],hv[1],hv[2],hv[3]);
        *(ushort4*)(ob + rb + O + ob0) = make_ushort4(lv[0],lv[1],lv[2],lv[3]);
      }
    }
  } else {
    float* pool = (float*)Og;
    #pragma unroll
    for(int mt=0;mt<MT;mt++){
      int ob0 = o0 + wid*WO + mt*16 + q*4;
      #pragma unroll
      for(int half=0;half<2;half++){
        int bm = 2*rt + half;
        int b = bm>>8, m = bm&255;
        #pragma unroll
        for(int r=0;r<4;r++){
          float s=sg[ob0+r]*BNS, bi=bg[ob0+r];
          float v = acc[mt][half*4+0][r]*s+bi;
          v = fmaxf(v, acc[mt][half*4+1][r]*s+bi);
          v = fmaxf(v, acc[mt][half*4+2][r]*s+bi);
          v = fmaxf(v, acc[mt][half*4+3][r]*s+bi);
          v = fmaxf(v, 0.f);
          v = fmaxf(v, __shfl_xor(v,1));
          v = fmaxf(v, __shfl_xor(v,2));
          v = fmaxf(v, __shfl_xor(v,4));
          v = fmaxf(v, __shfl_xor(v,8));
          if(l15==0) pool[((size_t)b*512 + ob0+r)*256 + m] = v;
        }
      }
    }
  }
}

// ------- fused head: red -> sc1 -> sc2, one block = (b, 4 cols) -------------
// P/X1/H staged in LDS stride-5 (conflict-free); x1 kept in regs for residual.
__global__ __launch_bounds__(256) void k_headf(const float* __restrict__ Wt_red,
    const float* __restrict__ Wt_s1, const float* __restrict__ Wt_s2,
    const float* __restrict__ pool, float* __restrict__ Og,
    const float* __restrict__ red_g, const float* __restrict__ red_b,
    const float* __restrict__ n1g, const float* __restrict__ n1b,
    const float* __restrict__ s1b, const float* __restrict__ s2b,
    const float* __restrict__ n2g, const float* __restrict__ n2b){
  __shared__ float P[512*5];
  __shared__ float X1[256*5];
  __shared__ float H[256*5];
  int g = blockIdx.x;
  int b = g>>6, mg = g&63;
  int m0 = mg*4;
  int o = threadIdx.x;
  // stage P[512][4]
  #pragma unroll
  for(int i=0;i<2;i++){
    int c = o + i*256;
    float4 v = *(const float4*)&pool[((size_t)b*512+c)*256 + m0];
    P[c*5+0]=v.x; P[c*5+1]=v.y; P[c*5+2]=v.z; P[c*5+3]=v.w;
  }
  __syncthreads();
  float acc[4];
  // red: K=512
  acc[0]=acc[1]=acc[2]=acc[3]=0.f;
  for(int c=0;c<512;c++){
    float w = Wt_red[c*256+o];
    #pragma unroll
    for(int j=0;j<4;j++) acc[j] += w*P[c*5+j];
  }
  float x1r[4];
  {
    float s=red_g[o]*BNS, bi=red_b[o], s1=n1g[o]*BNS, b1=n1b[o];
    #pragma unroll
    for(int j=0;j<4;j++){
      float r=fmaxf(acc[j]*s+bi,0.f);
      x1r[j]=2.f*r*s1+b1;
      X1[o*5+j]=x1r[j];
    }
  }
  __syncthreads();
  // sc1: K=256
  acc[0]=acc[1]=acc[2]=acc[3]=0.f;
  for(int c=0;c<256;c++){
    float w = Wt_s1[c*256+o];
    #pragma unroll
    for(int j=0;j<4;j++) acc[j] += w*X1[c*5+j];
  }
  {
    float bi=s1b[o];
    #pragma unroll
    for(int j=0;j<4;j++) H[o*5+j]=fmaxf(acc[j]+bi,0.f);
  }
  __syncthreads();
  // sc2 + residual + bn2
  acc[0]=acc[1]=acc[2]=acc[3]=0.f;
  for(int c=0;c<256;c++){
    float w = Wt_s2[c*256+o];
    #pragma unroll
    for(int j=0;j<4;j++) acc[j] += w*H[c*5+j];
  }
  {
    float bi=s2b[o], s2=n2g[o]*BNS, b2=n2b[o];
    float v[4];
    #pragma unroll
    for(int j=0;j<4;j++){ float u=x1r[j]+acc[j]+bi; v[j]=u*s2+b2; }
    *(float4*)&Og[((size_t)b*256+o)*256 + m0] = make_float4(v[0],v[1],v[2],v[3]);
  }
}

extern "C" void kernel_launch(void* const* d_in, const int* in_sizes, int n_in,
                              void* d_out, int out_size, void* d_ws, size_t ws_size,
                              hipStream_t stream){
  const float* xyz     =(const float*)d_in[0];
  const float* feats   =(const float*)d_in[1];
  const float* e1_w    =(const float*)d_in[2];
  const float* e1_g    =(const float*)d_in[3];
  const float* e1_b    =(const float*)d_in[4];
  const float* e2_w    =(const float*)d_in[5];
  const float* e2_g    =(const float*)d_in[6];
  const float* e2_b    =(const float*)d_in[7];
  const float* cal1_w  =(const float*)d_in[8];
  const float* cal1_g  =(const float*)d_in[9];
  const float* cal1_b  =(const float*)d_in[10];
  const float* cal2_w  =(const float*)d_in[11];
  const float* cal2_bias=(const float*)d_in[12];
  const float* exp1_w  =(const float*)d_in[13];
  const float* exp1_g  =(const float*)d_in[14];
  const float* exp1_b  =(const float*)d_in[15];
  const float* exp2_w  =(const float*)d_in[16];
  const float* exp2_g  =(const float*)d_in[17];
  const float* exp2_b  =(const float*)d_in[18];
  const float* red_w   =(const float*)d_in[19];
  const float* red_g   =(const float*)d_in[20];
  const float* red_b   =(const float*)d_in[21];
  const float* sc1_w   =(const float*)d_in[22];
  const float* sc1_b   =(const float*)d_in[23];
  const float* sc2_w   =(const float*)d_in[24];
  const float* sc2_b   =(const float*)d_in[25];
  const float* sc_n1_g =(const float*)d_in[26];
  const float* sc_n1_b =(const float*)d_in[27];
  const float* sc_n2_g =(const float*)d_in[28];
  const float* sc_n2_b =(const float*)d_in[29];

  char* wsb=(char*)d_ws;
  int*            idx =(int*)           (wsb);                    // 2 MB
  unsigned short* cats=(unsigned short*)(wsb + 10485760);         // 24 MB [row][2][192]
  unsigned short* p1s =(unsigned short*)(wsb + 35651584);         // 32 MB [row][2][256]
  float*          pool=(float*)         (wsb + 69206016);         // 1 MB
  unsigned short* Whi =(unsigned short*)(wsb + 75497472);         // 448 KB
  unsigned short* Wlo =(unsigned short*)(wsb + 76021760);         // 448 KB
  float*          Wt_red=(float*)       (wsb + 76546048);         // 512 KB
  float*          Wt_s1 =(float*)       (wsb + 77070336);         // 256 KB
  float*          Wt_s2 =(float*)       (wsb + 77332480);         // 256 KB
  unsigned short* e1e_h=Whi;          unsigned short* e1e_l=Wlo;          // 128x64
  unsigned short* e2e_h=Whi+8192;     unsigned short* e2e_l=Wlo+8192;     // 256x64
  unsigned short* e1w_h=Whi+49152;    unsigned short* e1w_l=Wlo+49152;    // 256x192
  unsigned short* e2w_h=Whi+98304;    unsigned short* e2w_l=Wlo+98304;    // 512x256

  k_prep      <<<1152,256,0,stream>>>(e1_w,e2_w,cal1_w,cal2_w,exp1_w,exp2_w,Whi,Wlo,
                                      red_w,sc1_w,sc2_w,Wt_red,Wt_s1,Wt_s2);
  k_knne12    <<<512,256,0,stream>>>(xyz,feats,e1e_h,e1e_l,e2e_h,e2e_l,idx,
                                     e1_g,e1_b,e2_g,e2_b,cats);
  k_cal       <<<256,256,0,stream>>>(Whi,Wlo,cats,cal1_g,cal1_b,cal2_bias);
  k_mm2<192,128,0><<<dim3(256,2),256,0,stream>>>(e1w_h,e1w_l,cats,(void*)p1s,exp1_g,exp1_b,256);
  k_mm2<256,128,2><<<dim3(256,4),256,0,stream>>>(e2w_h,e2w_l,p1s,(void*)pool,exp2_g,exp2_b,512);
  k_headf     <<<128,256,0,stream>>>(Wt_red,Wt_s1,Wt_s2,pool,(float*)d_out,
                                     red_g,red_b,sc_n1_g,sc_n1_b,sc1_b,sc2_b,sc_n2_g,sc_n2_b);
}

// Round 12
// 263.157 us; speedup vs baseline: 1.0287x; 1.0287x over previous
//
#include <hip/hip_runtime.h>
#include <hip/hip_bf16.h>
#include <math.h>
#include <stddef.h>

#define DEV __device__ __forceinline__
__device__ const float BNS = 0.99999500003749968f; // 1/sqrt(1+1e-5)

typedef __bf16 bf16x8 __attribute__((ext_vector_type(8)));
typedef float  f32x4  __attribute__((ext_vector_type(4)));

DEV unsigned short f2bs(float v){
  union{ __hip_bfloat16 b; unsigned short u; } c; c.b=__float2bfloat16(v); return c.u;
}
DEV float bs2f(unsigned short u){
  union{ unsigned short u; __hip_bfloat16 b; } c; c.u=u; return __bfloat162float(c.b);
}

// Geometry: B=2, M=256 -> 512 bm groups, N=64 pts, KNN=16, CIN=64,
// edge1 O=64, edge2 O=128, SUMM=192, CALIB=64, EXP=256/512, OUT=256. f32 I/O.
// Split-bf16 activation layout: [row][2][K] ushort (hi row, lo row), row=bm*64+n.

// ------- fused prep: 6 weight splits + 3 head transposes in one launch ------
__global__ __launch_bounds__(256) void k_prep(const float* __restrict__ e1_w,
    const float* __restrict__ e2_w, const float* __restrict__ cal1_w,
    const float* __restrict__ cal2_w, const float* __restrict__ exp1_w,
    const float* __restrict__ exp2_w, unsigned short* __restrict__ Whi,
    unsigned short* __restrict__ Wlo,
    const float* __restrict__ red_w, const float* __restrict__ sc1_w,
    const float* __restrict__ sc2_w, float* __restrict__ Wt_red,
    float* __restrict__ Wt_s1, float* __restrict__ Wt_s2){
  __shared__ float s[32][33];
  int bid = blockIdx.x;
  if(bid < 896){
    const float* src; unsigned short *hi,*lo; int mode, O=0, i0;
    if(bid<32)      { src=e1_w;  hi=Whi;       lo=Wlo;       mode=1; O= 64; i0=bid*256; }
    else if(bid<96) { src=e2_w;  hi=Whi+8192;  lo=Wlo+8192;  mode=1; O=128; i0=(bid-32)*256; }
    else if(bid<144){ src=cal1_w;hi=Whi+24576; lo=Wlo+24576; mode=0;        i0=(bid-96)*256; }
    else if(bid<192){ src=cal2_w;hi=Whi+36864; lo=Wlo+36864; mode=0;        i0=(bid-144)*256; }
    else if(bid<384){ src=exp1_w;hi=Whi+49152; lo=Wlo+49152; mode=0;        i0=(bid-192)*256; }
    else            { src=exp2_w;hi=Whi+98304; lo=Wlo+98304; mode=0;        i0=(bid-384)*256; }
    int i = i0 + threadIdx.x;
    float v;
    if(mode==0) v = src[i];
    else { // edge rows: [W1 ; W2-W1] over [2O][64]
      int row=i>>6, c=i&63;
      v = (row<O) ? src[row*128+c] : (src[(row-O)*128+64+c]-src[(row-O)*128+c]);
    }
    unsigned short h=f2bs(v); hi[i]=h; lo[i]=f2bs(v-bs2f(h));
  } else {
    int lb = bid-896;
    const float* in; float* out; int O,K;
    if(lb<128){ in=red_w; out=Wt_red; O=256; K=512; }
    else if(lb<192){ in=sc1_w; out=Wt_s1; O=256; K=256; lb-=128; }
    else { in=sc2_w; out=Wt_s2; O=256; K=256; lb-=192; }
    int nt=O>>5;
    int to=lb%nt, tk=lb/nt;
    int c=threadIdx.x&31, r8=threadIdx.x>>5;
    #pragma unroll
    for(int p=0;p<4;p++){
      int r=r8+p*8;
      s[r][c]=in[(size_t)(to*32+r)*K + tk*32 + c];
    }
    __syncthreads();
    #pragma unroll
    for(int p=0;p<4;p++){
      int r=r8+p*8;
      out[(size_t)(tk*32+r)*O + to*32 + c]=s[c][r];
    }
  }
}

// -------- fused knn + edge1 + edge2: per bm, all in LDS ---------------------
__global__ __launch_bounds__(256) void k_knne12(const float* __restrict__ xyz,
    const float* __restrict__ feats,
    const unsigned short* __restrict__ W1h, const unsigned short* __restrict__ W1l,
    const unsigned short* __restrict__ W2h, const unsigned short* __restrict__ W2l,
    int* __restrict__ idxo, const float* __restrict__ g1, const float* __restrict__ b1,
    const float* __restrict__ g2, const float* __restrict__ b2,
    unsigned short* __restrict__ cat){
  __shared__ float bufA[64*65];   // zs
  __shared__ float bufB[64*65];   // ds
  __shared__ __align__(16) unsigned short sb[64*136]; // x split -> e1out split
  __shared__ int   ips[64*16];
  __shared__ float sx0[64], sx1[64], sx2[64], sxx[64];
  int bm = blockIdx.x;
  int tid = threadIdx.x, n = tid&63, s = tid>>6;
  int wid = tid>>6, lane = tid&63;
  int l15 = lane&15, q = lane>>4;
  if(s==0){
    const float* xp = xyz + (size_t)(bm*64+n)*3;
    float px=xp[0], py=xp[1], pz=xp[2];
    sx0[n]=px; sx1[n]=py; sx2[n]=pz; sxx[n]=px*px+py*py+pz*pz;
  }
  __syncthreads();
  // ---- phase 1: wave-local top-16 (pd in registers, 4 lanes/point) ----
  {
    int p = lane>>2, seg = lane&3;
    int n1 = wid*16 + p;
    float px=sx0[n1], py=sx1[n1], pz=sx2[n1], xxn=sxx[n1];
    float pdr[16];
    #pragma unroll
    for(int t=0;t<16;t++){
      int m = seg*16+t;
      pdr[t] = 2.f*(px*sx0[m]+py*sx1[m]+pz*sx2[m]) - xxn - sxx[m];
    }
    for(int j=0;j<16;j++){
      float bv=-3.4e38f; int bi=seg*16;
      #pragma unroll
      for(int t=0;t<16;t++){ if(pdr[t]>bv){bv=pdr[t]; bi=seg*16+t;} }  // strict >: lowest idx
      float ov=__shfl_xor(bv,1); int oi=__shfl_xor(bi,1);
      if(ov>bv || (ov==bv && oi<bi)){bv=ov;bi=oi;}
      ov=__shfl_xor(bv,2); oi=__shfl_xor(bi,2);
      if(ov>bv || (ov==bv && oi<bi)){bv=ov;bi=oi;}
      if(seg==0) ips[n1*16+j]=bi;
      if((bi>>4)==seg) pdr[bi&15]=-3.4e38f;
    }
  }
  // ---- phase 2: split x into sb ----
  {
    unsigned short* r = sb + n*136;
    if(s==0){
      float px=sx0[n], py=sx1[n], pz=sx2[n];
      unsigned short h;
      h=f2bs(px); r[0]=h; r[64]=f2bs(px-bs2f(h));
      h=f2bs(py); r[1]=h; r[65]=f2bs(py-bs2f(h));
      h=f2bs(pz); r[2]=h; r[66]=f2bs(pz-bs2f(h));
    }
    const float* fp = feats + (size_t)(bm*64+n)*61;
    #pragma unroll
    for(int t=0;t<16;t++){
      int cc = s*16+t;
      if(cc<61){
        float v=fp[cc]; unsigned short h=f2bs(v);
        r[3+cc]=h; r[64+3+cc]=f2bs(v-bs2f(h));
      }
    }
  }
  __syncthreads();
  #pragma unroll
  for(int t=0;t<4;t++) idxo[bm*1024 + tid*4 + t] = ips[tid*4 + t];
  // ---- phase 3: edge1 MFMA ----
  {
    int rbase = ((wid<2)?0:64) + (wid&1)*32;
    f32x4 acc[2][4];
    #pragma unroll
    for(int a=0;a<2;a++)
      #pragma unroll
      for(int d=0;d<4;d++) acc[a][d]=(f32x4){0.f,0.f,0.f,0.f};
    #pragma unroll
    for(int kc=0;kc<2;kc++){
      int k0=kc*32;
      size_t a0=(size_t)(rbase+l15)*64 + k0 + q*8;
      size_t a1=(size_t)(rbase+16+l15)*64 + k0 + q*8;
      bf16x8 a0h=*(const bf16x8*)(W1h+a0), a0l=*(const bf16x8*)(W1l+a0);
      bf16x8 a1h=*(const bf16x8*)(W1h+a1), a1l=*(const bf16x8*)(W1l+a1);
      #pragma unroll
      for(int nt=0;nt<4;nt++){
        int row = nt*16 + l15;
        bf16x8 bh = *(const bf16x8*)&sb[row*136 + k0 + q*8];
        bf16x8 bl = *(const bf16x8*)&sb[row*136 + 64 + k0 + q*8];
        acc[0][nt]=__builtin_amdgcn_mfma_f32_16x16x32_bf16(a0h,bh,acc[0][nt],0,0,0);
        acc[0][nt]=__builtin_amdgcn_mfma_f32_16x16x32_bf16(a0h,bl,acc[0][nt],0,0,0);
        acc[0][nt]=__builtin_amdgcn_mfma_f32_16x16x32_bf16(a0l,bh,acc[0][nt],0,0,0);
        acc[1][nt]=__builtin_amdgcn_mfma_f32_16x16x32_bf16(a1h,bh,acc[1][nt],0,0,0);
        acc[1][nt]=__builtin_amdgcn_mfma_f32_16x16x32_bf16(a1h,bl,acc[1][nt],0,0,0);
        acc[1][nt]=__builtin_amdgcn_mfma_f32_16x16x32_bf16(a1l,bh,acc[1][nt],0,0,0);
      }
    }
    __syncthreads();
    float* dst = (wid<2)? bufA : bufB;
    int ro = (wid&1)*32;
    #pragma unroll
    for(int mt=0;mt<2;mt++)
      #pragma unroll
      for(int nt=0;nt<4;nt++)
        #pragma unroll
        for(int rr=0;rr<4;rr++)
          dst[(ro+mt*16+q*4+rr)*65 + nt*16+l15] = acc[mt][nt][rr];
  }
  __syncthreads();
  // ---- phase 4: gather edge1; write cats[0:64) + e1out split into sb ----
  {
    int o = lane;
    float sc = g1[o]*BNS, bi = b1[o];
    #pragma unroll 4
    for(int j=0;j<16;j++){
      int nn = wid*16 + j;
      const int* ip = &ips[nn*16];
      float mz = -3.4e38f;
      #pragma unroll
      for(int k=0;k<16;k++) mz = fmaxf(mz, bufA[o*65 + ip[k]]);
      float v = fmaxf(sc*(mz + bufB[o*65 + nn]) + bi, 0.f);
      unsigned short hv = f2bs(v), lv = f2bs(v - bs2f(hv));
      size_t cb = ((size_t)bm*64+nn)*384 + o;
      cat[cb] = hv; cat[cb+192] = lv;
      sb[nn*136 + o] = hv; sb[nn*136 + 64 + o] = lv;  // x dead after phase 3
    }
  }
  // ---- phase 5: edge2 (2 chunks of 64 o) from sb ----
  for(int ch=0; ch<2; ch++){
    __syncthreads();
    int rbase = ((wid<2)?0:128) + ch*64 + (wid&1)*32;
    f32x4 acc[2][4];
    #pragma unroll
    for(int a=0;a<2;a++)
      #pragma unroll
      for(int d=0;d<4;d++) acc[a][d]=(f32x4){0.f,0.f,0.f,0.f};
    #pragma unroll
    for(int kc=0;kc<2;kc++){
      int k0=kc*32;
      size_t a0=(size_t)(rbase+l15)*64 + k0 + q*8;
      size_t a1=(size_t)(rbase+16+l15)*64 + k0 + q*8;
      bf16x8 a0h=*(const bf16x8*)(W2h+a0), a0l=*(const bf16x8*)(W2l+a0);
      bf16x8 a1h=*(const bf16x8*)(W2h+a1), a1l=*(const bf16x8*)(W2l+a1);
      #pragma unroll
      for(int nt=0;nt<4;nt++){
        int row = nt*16 + l15;
        bf16x8 bh = *(const bf16x8*)&sb[row*136 + k0 + q*8];
        bf16x8 bl = *(const bf16x8*)&sb[row*136 + 64 + k0 + q*8];
        acc[0][nt]=__builtin_amdgcn_mfma_f32_16x16x32_bf16(a0h,bh,acc[0][nt],0,0,0);
        acc[0][nt]=__builtin_amdgcn_mfma_f32_16x16x32_bf16(a0h,bl,acc[0][nt],0,0,0);
        acc[0][nt]=__builtin_amdgcn_mfma_f32_16x16x32_bf16(a0l,bh,acc[0][nt],0,0,0);
        acc[1][nt]=__builtin_amdgcn_mfma_f32_16x16x32_bf16(a1h,bh,acc[1][nt],0,0,0);
        acc[1][nt]=__builtin_amdgcn_mfma_f32_16x16x32_bf16(a1h,bl,acc[1][nt],0,0,0);
        acc[1][nt]=__builtin_amdgcn_mfma_f32_16x16x32_bf16(a1l,bh,acc[1][nt],0,0,0);
      }
    }
    __syncthreads();
    float* dst = (wid<2)? bufA : bufB;
    int ro = (wid&1)*32;
    #pragma unroll
    for(int mt=0;mt<2;mt++)
      #pragma unroll
      for(int nt=0;nt<4;nt++)
        #pragma unroll
        for(int rr=0;rr<4;rr++)
          dst[(ro+mt*16+q*4+rr)*65 + nt*16+l15] = acc[mt][nt][rr];
    __syncthreads();
    int o = ch*64 + lane;
    float sc = g2[o]*BNS, bi = b2[o];
    #pragma unroll 4
    for(int j=0;j<16;j++){
      int nn = wid*16 + j;
      const int* ip = &ips[nn*16];
      float mz = -3.4e38f;
      #pragma unroll
      for(int k=0;k<16;k++) mz = fmaxf(mz, bufA[lane*65 + ip[k]]);
      float v = fmaxf(sc*(mz + bufB[lane*65 + nn]) + bi, 0.f);
      unsigned short hv = f2bs(v);
      size_t cb = ((size_t)bm*64+nn)*384 + 64 + o;
      cat[cb] = hv; cat[cb+192] = f2bs(v - bs2f(hv));
    }
  }
}

// ---------------- fused cal1+cal2+gate: one block = 128 rows ----------------
__global__ __launch_bounds__(256) void k_cal(
    const unsigned short* __restrict__ Whi, const unsigned short* __restrict__ Wlo,
    unsigned short* __restrict__ cats,
    const float* __restrict__ c1g, const float* __restrict__ c1b,
    const float* __restrict__ c2bias){
  const unsigned short* c1w_h = Whi+24576; const unsigned short* c1w_l = Wlo+24576;
  const unsigned short* c2w_h = Whi+36864; const unsigned short* c2w_l = Wlo+36864;
  __shared__ __align__(16) unsigned short sW[64*64];
  __shared__ __align__(16) unsigned short sX[128*64];
  __shared__ __align__(16) unsigned short c1L[128*136];
  int rt = blockIdx.x;
  int tid = threadIdx.x, wid = tid>>6, lane = tid&63;
  int l15 = lane&15, q = lane>>4;
  f32x4 acc1[8];
  #pragma unroll
  for(int d=0;d<8;d++) acc1[d]=(f32x4){0.f,0.f,0.f,0.f};
  size_t xbase = (size_t)rt*128*384;
  for(int kc=0;kc<6;kc++){
    int k0=kc*32;
    __syncthreads();
    #pragma unroll
    for(int i=0;i<2;i++){
      int U = tid + i*256;
      int r = U>>3, up = U&7, u = up ^ (r&7);
      const unsigned short* src = (u<4)
        ? (c1w_h + (size_t)r*192 + k0 + u*8)
        : (c1w_l + (size_t)r*192 + k0 + (u-4)*8);
      *(uint4*)&sW[U*8] = *(const uint4*)src;
    }
    #pragma unroll
    for(int i=0;i<4;i++){
      int U = tid + i*256;
      int r = U>>3, up = U&7, u = up ^ (r&7);
      const unsigned short* src = cats + xbase + (size_t)r*384
        + (u<4 ? (size_t)(k0 + u*8) : (size_t)(192 + k0 + (u-4)*8));
      *(uint4*)&sX[U*8] = *(const uint4*)src;
    }
    __syncthreads();
    int o = wid*16 + l15;
    bf16x8 wh = *(const bf16x8*)&sW[(o*8 + ((  q) ^ (o&7)))*8];
    bf16x8 wl = *(const bf16x8*)&sW[(o*8 + ((4+q) ^ (o&7)))*8];
    #pragma unroll
    for(int nf=0;nf<8;nf++){
      int r = nf*16 + l15;
      bf16x8 xh = *(const bf16x8*)&sX[(r*8 + ((  q) ^ (r&7)))*8];
      bf16x8 xl = *(const bf16x8*)&sX[(r*8 + ((4+q) ^ (r&7)))*8];
      acc1[nf]=__builtin_amdgcn_mfma_f32_16x16x32_bf16(wh,xh,acc1[nf],0,0,0);
      acc1[nf]=__builtin_amdgcn_mfma_f32_16x16x32_bf16(wh,xl,acc1[nf],0,0,0);
      acc1[nf]=__builtin_amdgcn_mfma_f32_16x16x32_bf16(wl,xh,acc1[nf],0,0,0);
    }
  }
  {
    int ob0 = wid*16 + q*4;
    float s0[4], b0[4];
    #pragma unroll
    for(int r=0;r<4;r++){ s0[r]=c1g[ob0+r]*BNS; b0[r]=c1b[ob0+r]; }
    #pragma unroll
    for(int nf=0;nf<8;nf++){
      int n = nf*16 + l15;
      unsigned short hv[4], lv[4];
      #pragma unroll
      for(int r=0;r<4;r++){
        float v = fmaxf(acc1[nf][r]*s0[r]+b0[r], 0.f);
        hv[r]=f2bs(v); lv[r]=f2bs(v - bs2f(hv[r]));
      }
      *(ushort4*)&c1L[n*136 + ob0]      = make_ushort4(hv[0],hv[1],hv[2],hv[3]);
      *(ushort4*)&c1L[n*136 + 64 + ob0] = make_ushort4(lv[0],lv[1],lv[2],lv[3]);
    }
  }
  __syncthreads();
  f32x4 acc2[3][8];
  #pragma unroll
  for(int a=0;a<3;a++)
    #pragma unroll
    for(int d=0;d<8;d++) acc2[a][d]=(f32x4){0.f,0.f,0.f,0.f};
  #pragma unroll
  for(int kc=0;kc<2;kc++){
    int k0=kc*32;
    bf16x8 ah[3], al[3];
    #pragma unroll
    for(int mt=0;mt<3;mt++){
      int o = wid*48 + mt*16 + l15;
      ah[mt]=*(const bf16x8*)(c2w_h + (size_t)o*64 + k0 + q*8);
      al[mt]=*(const bf16x8*)(c2w_l + (size_t)o*64 + k0 + q*8);
    }
    #pragma unroll
    for(int nf=0;nf<8;nf++){
      int n = nf*16 + l15;
      bf16x8 bh = *(const bf16x8*)&c1L[n*136 + k0 + q*8];
      bf16x8 bl = *(const bf16x8*)&c1L[n*136 + 64 + k0 + q*8];
      #pragma unroll
      for(int mt=0;mt<3;mt++){
        acc2[mt][nf]=__builtin_amdgcn_mfma_f32_16x16x32_bf16(ah[mt],bh,acc2[mt][nf],0,0,0);
        acc2[mt][nf]=__builtin_amdgcn_mfma_f32_16x16x32_bf16(ah[mt],bl,acc2[mt][nf],0,0,0);
        acc2[mt][nf]=__builtin_amdgcn_mfma_f32_16x16x32_bf16(al[mt],bh,acc2[mt][nf],0,0,0);
      }
    }
  }
  #pragma unroll
  for(int mt=0;mt<3;mt++){
    int ob0 = wid*48 + mt*16 + q*4;
    float bi[4];
    #pragma unroll
    for(int r=0;r<4;r++) bi[r]=c2bias[ob0+r];
    #pragma unroll
    for(int nf=0;nf<8;nf++){
      size_t row = (size_t)rt*128 + nf*16 + l15;
      size_t rb = row*384;
      ushort4 hv = *(ushort4*)(cats + rb + ob0);
      ushort4 lv = *(ushort4*)(cats + rb + 192 + ob0);
      unsigned short h[4]={hv.x,hv.y,hv.z,hv.w}, l[4]={lv.x,lv.y,lv.z,lv.w};
      #pragma unroll
      for(int r=0;r<4;r++){
        float g = 1.f/(1.f+__expf(-(acc2[mt][nf][r]+bi[r])));
        float f = (bs2f(h[r])+bs2f(l[r]))*g;
        h[r]=f2bs(f); l[r]=f2bs(f-bs2f(h[r]));
      }
      *(ushort4*)(cats + rb + ob0)       = make_ushort4(h[0],h[1],h[2],h[3]);
      *(ushort4*)(cats + rb + 192 + ob0) = make_ushort4(l[0],l[1],l[2],l[3]);
    }
  }
}

// ---------------- LDS-tiled split-bf16 MFMA GEMM ---------------------------
template<int K, int BO, int EPI>
__global__ __launch_bounds__(256) void k_mm2(
    const unsigned short* __restrict__ Whi, const unsigned short* __restrict__ Wlo,
    const unsigned short* __restrict__ X, void* __restrict__ Og,
    const float* __restrict__ sg, const float* __restrict__ bg, int O){
  constexpr int WO = BO/4;
  constexpr int MT = WO/16;
  constexpr int WUNITS = BO*8;
  __shared__ __align__(16) unsigned short sW[BO*64];
  __shared__ __align__(16) unsigned short sX[128*64];
  int rt = blockIdx.x;
  int o0 = blockIdx.y*BO;
  int tid = threadIdx.x, wid = tid>>6, lane = tid&63;
  int l15 = lane&15, q = lane>>4;
  f32x4 acc[MT][8];
  #pragma unroll
  for(int a=0;a<MT;a++)
    #pragma unroll
    for(int d=0;d<8;d++) acc[a][d]=(f32x4){0.f,0.f,0.f,0.f};
  size_t xbase = (size_t)rt*128*2*K;
  for(int kc=0; kc<K/32; kc++){
    int k0 = kc*32;
    __syncthreads();
    #pragma unroll
    for(int i=0;i<WUNITS/256;i++){
      int U = tid + i*256;
      int r = U>>3, up = U&7, u = up ^ (r&7);
      const unsigned short* src = (u<4)
        ? (Whi + (size_t)(o0+r)*K + k0 + u*8)
        : (Wlo + (size_t)(o0+r)*K + k0 + (u-4)*8);
      *(uint4*)&sW[U*8] = *(const uint4*)src;
    }
    #pragma unroll
    for(int i=0;i<4;i++){
      int U = tid + i*256;
      int r = U>>3, up = U&7, u = up ^ (r&7);
      const unsigned short* src = X + xbase + (size_t)r*2*K
        + (u<4 ? (size_t)(k0 + u*8) : (size_t)(K + k0 + (u-4)*8));
      *(uint4*)&sX[U*8] = *(const uint4*)src;
    }
    __syncthreads();
    bf16x8 wf[MT][2];
    #pragma unroll
    for(int mt=0;mt<MT;mt++){
      int o = wid*WO + mt*16 + l15;
      wf[mt][0] = *(const bf16x8*)&sW[(o*8 + ((  q) ^ (o&7)))*8];
      wf[mt][1] = *(const bf16x8*)&sW[(o*8 + ((4+q) ^ (o&7)))*8];
    }
    #pragma unroll
    for(int nf=0;nf<8;nf++){
      int r = nf*16 + l15;
      bf16x8 xh = *(const bf16x8*)&sX[(r*8 + ((  q) ^ (r&7)))*8];
      bf16x8 xl = *(const bf16x8*)&sX[(r*8 + ((4+q) ^ (r&7)))*8];
      #pragma unroll
      for(int mt=0;mt<MT;mt++){
        acc[mt][nf]=__builtin_amdgcn_mfma_f32_16x16x32_bf16(wf[mt][0],xh,acc[mt][nf],0,0,0);
        acc[mt][nf]=__builtin_amdgcn_mfma_f32_16x16x32_bf16(wf[mt][0],xl,acc[mt][nf],0,0,0);
        acc[mt][nf]=__builtin_amdgcn_mfma_f32_16x16x32_bf16(wf[mt][1],xh,acc[mt][nf],0,0,0);
      }
    }
  }
  if(EPI==0){
    unsigned short* ob = (unsigned short*)Og;
    #pragma unroll
    for(int mt=0;mt<MT;mt++){
      int ob0 = o0 + wid*WO + mt*16 + q*4;
      float s0[4], b0[4];
      #pragma unroll
      for(int r=0;r<4;r++){ s0[r]=sg[ob0+r]*BNS; b0[r]=bg[ob0+r]; }
      #pragma unroll
      for(int nf=0;nf<8;nf++){
        size_t row = (size_t)rt*128 + nf*16 + l15;
        size_t rb = row*2*O;
        unsigned short hv[4], lv[4];
        #pragma unroll
        for(int r=0;r<4;r++){
          float v = fmaxf(acc[mt][nf][r]*s0[r]+b0[r], 0.f);
          hv[r]=f2bs(v); lv[r]=f2bs(v - bs2f(hv[r]));
        }
        *(ushort4*)(ob + rb + ob0)     = make_ushort4(hv[0],hv[1],hv[2],hv[3]);
        *(ushort4*)(ob + rb + O + ob0) = make_ushort4(lv[0],lv[1],lv[2],lv[3]);
      }
    }
  } else {
    float* pool = (float*)Og;
    #pragma unroll
    for(int mt=0;mt<MT;mt++){
      int ob0 = o0 + wid*WO + mt*16 + q*4;
      #pragma unroll
      for(int half=0;half<2;half++){
        int bm = 2*rt + half;
        int b = bm>>8, m = bm&255;
        #pragma unroll
        for(int r=0;r<4;r++){
          float s=sg[ob0+r]*BNS, bi=bg[ob0+r];
          float v = acc[mt][half*4+0][r]*s+bi;
          v = fmaxf(v, acc[mt][half*4+1][r]*s+bi);
          v = fmaxf(v, acc[mt][half*4+2][r]*s+bi);
          v = fmaxf(v, acc[mt][half*4+3][r]*s+bi);
          v = fmaxf(v, 0.f);
          v = fmaxf(v, __shfl_xor(v,1));
          v = fmaxf(v, __shfl_xor(v,2));
          v = fmaxf(v, __shfl_xor(v,4));
          v = fmaxf(v, __shfl_xor(v,8));
          if(l15==0) pool[((size_t)b*512 + ob0+r)*256 + m] = v;
        }
      }
    }
  }
}

// ------- fused head: red -> sc1 -> sc2, one block = (b, 2 cols) -------------
// 256 blocks; K-loops unrolled x8 for load ILP; LDS stride-3 staging.
__global__ __launch_bounds__(256) void k_headf(const float* __restrict__ Wt_red,
    const float* __restrict__ Wt_s1, const float* __restrict__ Wt_s2,
    const float* __restrict__ pool, float* __restrict__ Og,
    const float* __restrict__ red_g, const float* __restrict__ red_b,
    const float* __restrict__ n1g, const float* __restrict__ n1b,
    const float* __restrict__ s1b, const float* __restrict__ s2b,
    const float* __restrict__ n2g, const float* __restrict__ n2b){
  __shared__ float P[512*3];
  __shared__ float X1[256*3];
  __shared__ float H[256*3];
  int g = blockIdx.x;
  int b = g>>7, mg = g&127;
  int m0 = mg*2;
  int o = threadIdx.x;
  // stage P[512][2]
  #pragma unroll
  for(int i=0;i<2;i++){
    int c = o + i*256;
    float2 v = *(const float2*)&pool[((size_t)b*512+c)*256 + m0];
    P[c*3+0]=v.x; P[c*3+1]=v.y;
  }
  __syncthreads();
  float a0,a1;
  // red: K=512
  a0=a1=0.f;
  #pragma unroll 8
  for(int c=0;c<512;c++){
    float w = Wt_red[c*256+o];
    a0 += w*P[c*3]; a1 += w*P[c*3+1];
  }
  float x0r,x1r;
  {
    float s=red_g[o]*BNS, bi=red_b[o], s1=n1g[o]*BNS, b1=n1b[o];
    float r0=fmaxf(a0*s+bi,0.f), r1=fmaxf(a1*s+bi,0.f);
    x0r=2.f*r0*s1+b1; x1r=2.f*r1*s1+b1;
    X1[o*3]=x0r; X1[o*3+1]=x1r;
  }
  __syncthreads();
  // sc1: K=256
  a0=a1=0.f;
  #pragma unroll 8
  for(int c=0;c<256;c++){
    float w = Wt_s1[c*256+o];
    a0 += w*X1[c*3]; a1 += w*X1[c*3+1];
  }
  {
    float bi=s1b[o];
    H[o*3]=fmaxf(a0+bi,0.f); H[o*3+1]=fmaxf(a1+bi,0.f);
  }
  __syncthreads();
  // sc2 + residual + bn2
  a0=a1=0.f;
  #pragma unroll 8
  for(int c=0;c<256;c++){
    float w = Wt_s2[c*256+o];
    a0 += w*H[c*3]; a1 += w*H[c*3+1];
  }
  {
    float bi=s2b[o], s2=n2g[o]*BNS, b2=n2b[o];
    float v0=(x0r+a0+bi)*s2+b2, v1=(x1r+a1+bi)*s2+b2;
    *(float2*)&Og[((size_t)b*256+o)*256 + m0] = make_float2(v0,v1);
  }
}

extern "C" void kernel_launch(void* const* d_in, const int* in_sizes, int n_in,
                              void* d_out, int out_size, void* d_ws, size_t ws_size,
                              hipStream_t stream){
  const float* xyz     =(const float*)d_in[0];
  const float* feats   =(const float*)d_in[1];
  const float* e1_w    =(const float*)d_in[2];
  const float* e1_g    =(const float*)d_in[3];
  const float* e1_b    =(const float*)d_in[4];
  const float* e2_w    =(const float*)d_in[5];
  const float* e2_g    =(const float*)d_in[6];
  const float* e2_b    =(const float*)d_in[7];
  const float* cal1_w  =(const float*)d_in[8];
  const float* cal1_g  =(const float*)d_in[9];
  const float* cal1_b  =(const float*)d_in[10];
  const float* cal2_w  =(const float*)d_in[11];
  const float* cal2_bias=(const float*)d_in[12];
  const float* exp1_w  =(const float*)d_in[13];
  const float* exp1_g  =(const float*)d_in[14];
  const float* exp1_b  =(const float*)d_in[15];
  const float* exp2_w  =(const float*)d_in[16];
  const float* exp2_g  =(const float*)d_in[17];
  const float* exp2_b  =(const float*)d_in[18];
  const float* red_w   =(const float*)d_in[19];
  const float* red_g   =(const float*)d_in[20];
  const float* red_b   =(const float*)d_in[21];
  const float* sc1_w   =(const float*)d_in[22];
  const float* sc1_b   =(const float*)d_in[23];
  const float* sc2_w   =(const float*)d_in[24];
  const float* sc2_b   =(const float*)d_in[25];
  const float* sc_n1_g =(const float*)d_in[26];
  const float* sc_n1_b =(const float*)d_in[27];
  const float* sc_n2_g =(const float*)d_in[28];
  const float* sc_n2_b =(const float*)d_in[29];

  char* wsb=(char*)d_ws;
  int*            idx =(int*)           (wsb);                    // 2 MB
  unsigned short* cats=(unsigned short*)(wsb + 10485760);         // 24 MB [row][2][192]
  unsigned short* p1s =(unsigned short*)(wsb + 35651584);         // 32 MB [row][2][256]
  float*          pool=(float*)         (wsb + 69206016);         // 1 MB
  unsigned short* Whi =(unsigned short*)(wsb + 75497472);         // 448 KB
  unsigned short* Wlo =(unsigned short*)(wsb + 76021760);         // 448 KB
  float*          Wt_red=(float*)       (wsb + 76546048);         // 512 KB
  float*          Wt_s1 =(float*)       (wsb + 77070336);         // 256 KB
  float*          Wt_s2 =(float*)       (wsb + 77332480);         // 256 KB
  unsigned short* e1e_h=Whi;          unsigned short* e1e_l=Wlo;          // 128x64
  unsigned short* e2e_h=Whi+8192;     unsigned short* e2e_l=Wlo+8192;     // 256x64
  unsigned short* e1w_h=Whi+49152;    unsigned short* e1w_l=Wlo+49152;    // 256x192
  unsigned short* e2w_h=Whi+98304;    unsigned short* e2w_l=Wlo+98304;    // 512x256

  k_prep      <<<1152,256,0,stream>>>(e1_w,e2_w,cal1_w,cal2_w,exp1_w,exp2_w,Whi,Wlo,
                                      red_w,sc1_w,sc2_w,Wt_red,Wt_s1,Wt_s2);
  k_knne12    <<<512,256,0,stream>>>(xyz,feats,e1e_h,e1e_l,e2e_h,e2e_l,idx,
                                     e1_g,e1_b,e2_g,e2_b,cats);
  k_cal       <<<256,256,0,stream>>>(Whi,Wlo,cats,cal1_g,cal1_b,cal2_bias);
  k_mm2<192,128,0><<<dim3(256,2),256,0,stream>>>(e1w_h,e1w_l,cats,(void*)p1s,exp1_g,exp1_b,256);
  k_mm2<256,128,2><<<dim3(256,4),256,0,stream>>>(e2w_h,e2w_l,p1s,(void*)pool,exp2_g,exp2_b,512);
  k_headf     <<<256,256,0,stream>>>(Wt_red,Wt_s1,Wt_s2,pool,(float*)d_out,
                                     red_g,red_b,sc_n1_g,sc_n1_b,sc1_b,sc2_b,sc_n2_g,sc_n2_b);
}